// Round 1
// baseline (410.708 us; speedup 1.0000x reference)
//
#include <hip/hip_runtime.h>
#include <math.h>

// AlignQuantizer: group-wise (256 contiguous fp32) exponent-aligned truncation.
// result = sign(x) * floor( mant(x) * 2^(e - M + 10) ) * 2^(M - 10)
//   e = floor(log2(|x| + 1e-30)), M = max e over the group, mant = |x| * 2^-e.
// All scalings are exact powers of two -> bit-equal to the reference chain.

constexpr int GROUP_SIZE = 256;   // elements per quant group
constexpr int WAVES_PER_BLOCK = 4;

__global__ __launch_bounds__(256, 4)
void align_quant_kernel(const float* __restrict__ x,
                        float* __restrict__ out,
                        int num_groups) {
    const int wave = threadIdx.x >> 6;         // 0..3
    const int lane = threadIdx.x & 63;         // 0..63
    const long long g = (long long)blockIdx.x * WAVES_PER_BLOCK + wave;
    if (g >= num_groups) return;

    const size_t base = (size_t)g * GROUP_SIZE + (size_t)lane * 4;

    // One float4 per lane: wave covers the full 1 KB group, coalesced.
    const float4 v = *reinterpret_cast<const float4*>(x + base);

    const float a0 = fabsf(v.x), a1 = fabsf(v.y), a2 = fabsf(v.z), a3 = fabsf(v.w);

    // Exponent exactly as the reference computes it (log2-based, +1e-30 bias).
    const float e0 = floorf(log2f(a0 + 1e-30f));
    const float e1 = floorf(log2f(a1 + 1e-30f));
    const float e2 = floorf(log2f(a2 + 1e-30f));
    const float e3 = floorf(log2f(a3 + 1e-30f));

    // Wave-wide max of exponents (group max). 64 lanes -> 6 butterfly steps.
    float m = fmaxf(fmaxf(e0, e1), fmaxf(e2, e3));
    #pragma unroll
    for (int off = 32; off > 0; off >>= 1)
        m = fmaxf(m, __shfl_xor(m, off, 64));

    const int Mi = (int)m;

    float4 r;
    {
        const int ei = (int)e0;
        const float mant = ldexpf(a0, -ei);                    // |x| / 2^e   (exact)
        const float fl = floorf(ldexpf(mant, ei - Mi + 10));   // floor(aligned * 2^10)
        r.x = copysignf(ldexpf(fl, Mi - 10), v.x);             // * 2^(M-10), restore sign
    }
    {
        const int ei = (int)e1;
        const float mant = ldexpf(a1, -ei);
        const float fl = floorf(ldexpf(mant, ei - Mi + 10));
        r.y = copysignf(ldexpf(fl, Mi - 10), v.y);
    }
    {
        const int ei = (int)e2;
        const float mant = ldexpf(a2, -ei);
        const float fl = floorf(ldexpf(mant, ei - Mi + 10));
        r.z = copysignf(ldexpf(fl, Mi - 10), v.z);
    }
    {
        const int ei = (int)e3;
        const float mant = ldexpf(a3, -ei);
        const float fl = floorf(ldexpf(mant, ei - Mi + 10));
        r.w = copysignf(ldexpf(fl, Mi - 10), v.w);
    }

    *reinterpret_cast<float4*>(out + base) = r;
}

extern "C" void kernel_launch(void* const* d_in, const int* in_sizes, int n_in,
                              void* d_out, int out_size, void* d_ws, size_t ws_size,
                              hipStream_t stream) {
    const float* x = (const float*)d_in[0];
    float* out = (float*)d_out;

    const long long n = (long long)in_sizes[0];
    const int num_groups = (int)(n / GROUP_SIZE);
    const int blocks = (num_groups + WAVES_PER_BLOCK - 1) / WAVES_PER_BLOCK;

    align_quant_kernel<<<blocks, 256, 0, stream>>>(x, out, num_groups);
}

// Round 7
// 408.186 us; speedup vs baseline: 1.0062x; 1.0062x over previous
//
#include <hip/hip_runtime.h>
#include <math.h>

// AlignQuantizer: group-wise (256 contiguous fp32) exponent-aligned truncation.
//   e = floor(log2(|x| + 1e-30))   (log2f kept literally: bit-exact vs XLA, proven R1)
//   M = max e over group of 256
//   result = sign(x) * floor(|x| * 2^(10-M)) * 2^(M-10)
// Collapsed from the reference chain: mant*2^(e-M+10) == |x|*2^(10-M) exactly
// (power-of-two scalings are exact; subnormal-underflow cases floor to 0 on both paths).

constexpr int GROUP_SIZE = 256;   // elements per quant group
constexpr int WAVES_PER_BLOCK = 4;

// Native clang vector type: required by __builtin_nontemporal_load/store
// (HIP's float4 is a HIP_vector_type class and is rejected — R6 compile error).
typedef float f32x4 __attribute__((ext_vector_type(4)));

__global__ __launch_bounds__(256, 8)
void align_quant_kernel(const float* __restrict__ x,
                        float* __restrict__ out,
                        int num_groups) {
    const int wave = threadIdx.x >> 6;         // 0..3
    const int lane = threadIdx.x & 63;         // 0..63
    const int g = blockIdx.x * WAVES_PER_BLOCK + wave;
    if (g >= num_groups) return;

    const size_t base = (size_t)g * GROUP_SIZE + (size_t)lane * 4;

    // One 16B load per lane: wave covers the full 1 KB group, coalesced. NT: no reuse.
    const f32x4 v = __builtin_nontemporal_load(
        reinterpret_cast<const f32x4*>(x + base));

    const float a0 = fabsf(v.x), a1 = fabsf(v.y), a2 = fabsf(v.z), a3 = fabsf(v.w);

    // Exponent exactly as the reference computes it (log2-based, +1e-30 bias).
    const float e0 = floorf(log2f(a0 + 1e-30f));
    const float e1 = floorf(log2f(a1 + 1e-30f));
    const float e2 = floorf(log2f(a2 + 1e-30f));
    const float e3 = floorf(log2f(a3 + 1e-30f));

    // Wave-wide max of exponents (group max). 64 lanes -> 6 butterfly steps.
    float m = fmaxf(fmaxf(e0, e1), fmaxf(e2, e3));
    #pragma unroll
    for (int off = 32; off > 0; off >>= 1)
        m = fmaxf(m, __shfl_xor(m, off, 64));

    const int sh = 10 - (int)m;                // scale exponent: 2^(10-M)

    f32x4 r;
    r.x = copysignf(ldexpf(floorf(ldexpf(a0, sh)), -sh), v.x);
    r.y = copysignf(ldexpf(floorf(ldexpf(a1, sh)), -sh), v.y);
    r.z = copysignf(ldexpf(floorf(ldexpf(a2, sh)), -sh), v.z);
    r.w = copysignf(ldexpf(floorf(ldexpf(a3, sh)), -sh), v.w);

    __builtin_nontemporal_store(r, reinterpret_cast<f32x4*>(out + base));
}

extern "C" void kernel_launch(void* const* d_in, const int* in_sizes, int n_in,
                              void* d_out, int out_size, void* d_ws, size_t ws_size,
                              hipStream_t stream) {
    const float* x = (const float*)d_in[0];
    float* out = (float*)d_out;

    const long long n = (long long)in_sizes[0];
    const int num_groups = (int)(n / GROUP_SIZE);
    const int blocks = (num_groups + WAVES_PER_BLOCK - 1) / WAVES_PER_BLOCK;

    align_quant_kernel<<<blocks, 256, 0, stream>>>(x, out, num_groups);
}

// Round 10
// 406.859 us; speedup vs baseline: 1.0095x; 1.0033x over previous
//
#include <hip/hip_runtime.h>
#include <math.h>

// AlignQuantizer: group-wise (256 contiguous fp32) exponent-aligned truncation.
//   M = max_i floor(log2(|x_i| + 1e-30))  over the 256-group
//   result = sign(x) * floor(|x| * 2^(10-M)) * 2^(M-10)
//
// Two exact algebraic collapses vs the reference chain:
//  (1) mant*2^(e-M+10) == |x|*2^(10-M)  (power-of-two scalings exact),
//      so per-element exponents e_i cancel entirely.
//  (2) floor & log2 are monotone nondecreasing =>
//      max_i floor(log2(a_i+1e-30)) == floor(log2(max_i a_i + 1e-30)).
//      Only the group-max element's log2 rounding matters; log2f matched
//      XLA bit-for-bit on all elements in R1/R7 (absmax=0.0).
// => reduce max|x| with cheap v_max_f32 butterfly, ONE log2f afterwards.

constexpr int GROUP_SIZE = 256;   // elements per quant group
constexpr int WAVES_PER_BLOCK = 4;

// Native clang vector type: required by __builtin_nontemporal_load/store
// (HIP float4 is a class and is rejected — R6 compile error).
typedef float f32x4 __attribute__((ext_vector_type(4)));

__global__ __launch_bounds__(256, 8)
void align_quant_kernel(const float* __restrict__ x,
                        float* __restrict__ out,
                        int num_groups) {
    const int wave = threadIdx.x >> 6;         // 0..3
    const int lane = threadIdx.x & 63;         // 0..63
    const int g = blockIdx.x * WAVES_PER_BLOCK + wave;
    if (g >= num_groups) return;

    const size_t base = (size_t)g * GROUP_SIZE + (size_t)lane * 4;

    // One 16B load per lane: wave covers the full 1 KB group, coalesced. NT: no reuse.
    const f32x4 v = __builtin_nontemporal_load(
        reinterpret_cast<const f32x4*>(x + base));

    const float a0 = fabsf(v.x), a1 = fabsf(v.y), a2 = fabsf(v.z), a3 = fabsf(v.w);

    // Wave-wide max of |x| (group max). 64 lanes -> 6 butterfly steps of v_max_f32.
    float m = fmaxf(fmaxf(a0, a1), fmaxf(a2, a3));
    #pragma unroll
    for (int off = 32; off > 0; off >>= 1)
        m = fmaxf(m, __shfl_xor(m, off, 64));

    // Single transcendental per lane (same value in all lanes): M = floor(log2(amax+1e-30)).
    const int Mi = (int)floorf(log2f(m + 1e-30f));
    const int sh = 10 - Mi;                    // scale exponent: 2^(10-M)

    f32x4 r;
    r.x = copysignf(ldexpf(floorf(ldexpf(a0, sh)), -sh), v.x);
    r.y = copysignf(ldexpf(floorf(ldexpf(a1, sh)), -sh), v.y);
    r.z = copysignf(ldexpf(floorf(ldexpf(a2, sh)), -sh), v.z);
    r.w = copysignf(ldexpf(floorf(ldexpf(a3, sh)), -sh), v.w);

    __builtin_nontemporal_store(r, reinterpret_cast<f32x4*>(out + base));
}

extern "C" void kernel_launch(void* const* d_in, const int* in_sizes, int n_in,
                              void* d_out, int out_size, void* d_ws, size_t ws_size,
                              hipStream_t stream) {
    const float* x = (const float*)d_in[0];
    float* out = (float*)d_out;

    const long long n = (long long)in_sizes[0];
    const int num_groups = (int)(n / GROUP_SIZE);
    const int blocks = (num_groups + WAVES_PER_BLOCK - 1) / WAVES_PER_BLOCK;

    align_quant_kernel<<<blocks, 256, 0, stream>>>(x, out, num_groups);
}